// Round 1
// baseline (141.446 us; speedup 1.0000x reference)
//
#include <hip/hip_runtime.h>

// IoU3DLoss: per-element rotated 3D IoU (+DIoU) and masked-mean loss.
// One thread per box pair; all geometry in registers with compile-time
// indexing; bitonic network (32 slots) replaces the angular argsort.

__device__ __forceinline__ unsigned sortKey(float f) {
    unsigned u = __float_as_uint(f);
    // monotone map float -> uint (total order matching float <)
    return (u & 0x80000000u) ? ~u : (u | 0x80000000u);
}

__global__ __launch_bounds__(256) void iou3d_loss_kernel(
    const float* __restrict__ pred_iou,
    const float* __restrict__ pred_boxes,   // [M,7] x,y,z,w,h,l,alpha
    const float* __restrict__ gt_boxes,     // [M,8] x,y,z,w,h,l,sin,cos
    const int*   __restrict__ mask,
    float* __restrict__ sums,               // ws: [0]=contrib sum, [1]=mask count
    int M)
{
    const int gid = blockIdx.x * blockDim.x + threadIdx.x;
    float contrib = 0.0f, mfv = 0.0f;

    if (gid < M) {
        float b1[7];
        #pragma unroll
        for (int k = 0; k < 7; ++k) b1[k] = pred_boxes[(size_t)gid * 7 + k];
        float b2[8];
        #pragma unroll
        for (int k = 0; k < 8; ++k) b2[k] = gt_boxes[(size_t)gid * 8 + k];

        const float a1 = b1[6];
        const float a2 = atan2f(b2[6], b2[7]);
        const float cs1 = cosf(a1), sn1 = sinf(a1);
        const float cs2 = cosf(a2), sn2 = sinf(a2);

        const float xsg[4] = {0.5f, -0.5f, -0.5f, 0.5f};
        const float ysg[4] = {0.5f, 0.5f, -0.5f, -0.5f};

        float c1x[4], c1y[4], c2x[4], c2y[4];
        #pragma unroll
        for (int k = 0; k < 4; ++k) {
            float xx = xsg[k] * b1[3], yy = ysg[k] * b1[4];
            c1x[k] = xx * cs1 - yy * sn1 + b1[0];
            c1y[k] = xx * sn1 + yy * cs1 + b1[1];
            float x2 = xsg[k] * b2[3], y2 = ysg[k] * b2[4];
            c2x[k] = x2 * cs2 - y2 * sn2 + b2[0];
            c2y[k] = x2 * sn2 + y2 * cs2 + b2[1];
        }

        // candidate vertices: 0-3 c1 corners, 4-7 c2 corners, 8-23 edge xings
        float vx[32], vy[32];
        unsigned kkey[32];
        unsigned vmask = 0u;
        const float eps = 1e-6f;

        {   // c1 corners inside box2
            float ax = c2x[0], ay = c2y[0];
            float abx = c2x[1] - ax, aby = c2y[1] - ay;
            float adx = c2x[3] - ax, ady = c2y[3] - ay;
            float ab2 = abx * abx + aby * aby;
            float ad2 = adx * adx + ady * ady;
            #pragma unroll
            for (int k = 0; k < 4; ++k) {
                vx[k] = c1x[k]; vy[k] = c1y[k];
                float apx = c1x[k] - ax, apy = c1y[k] - ay;
                float pab = (apx * abx + apy * aby) / ab2;
                float pad = (apx * adx + apy * ady) / ad2;
                if (pab > -eps && pab < 1.0f + eps && pad > -eps && pad < 1.0f + eps)
                    vmask |= 1u << k;
            }
        }
        {   // c2 corners inside box1
            float ax = c1x[0], ay = c1y[0];
            float abx = c1x[1] - ax, aby = c1y[1] - ay;
            float adx = c1x[3] - ax, ady = c1y[3] - ay;
            float ab2 = abx * abx + aby * aby;
            float ad2 = adx * adx + ady * ady;
            #pragma unroll
            for (int k = 0; k < 4; ++k) {
                vx[4 + k] = c2x[k]; vy[4 + k] = c2y[k];
                float apx = c2x[k] - ax, apy = c2y[k] - ay;
                float pab = (apx * abx + apy * aby) / ab2;
                float pad = (apx * adx + apy * ady) / ad2;
                if (pab > -eps && pab < 1.0f + eps && pad > -eps && pad < 1.0f + eps)
                    vmask |= 1u << (4 + k);
            }
        }
        // segment intersections (edge l of box1 x edge m of box2)
        #pragma unroll
        for (int l = 0; l < 4; ++l) {
            float x1 = c1x[l], y1 = c1y[l];
            float x2 = c1x[(l + 1) & 3], y2 = c1y[(l + 1) & 3];
            #pragma unroll
            for (int m = 0; m < 4; ++m) {
                float x3 = c2x[m], y3 = c2y[m];
                float x4 = c2x[(m + 1) & 3], y4 = c2y[(m + 1) & 3];
                float den  = (x4 - x3) * (y1 - y2) - (x1 - x2) * (y4 - y3);
                bool  z    = (den == 0.0f);
                float safe = z ? 1.0f : den;
                float numt = (y4 - y3) * (x1 - x3) - (x4 - x3) * (y1 - y3);
                float numu = (y1 - y2) * (x1 - x3) - (x1 - x2) * (y1 - y3);
                float t = z ? -1.0f : numt / safe;
                float u = z ? -1.0f : (-numu) / safe;
                bool ok = (t > 0.0f) && (t < 1.0f) && (u > 0.0f) && (u < 1.0f);
                int v = 8 + l * 4 + m;
                vx[v] = ok ? x1 + t * (x2 - x1) : 0.0f;
                vy[v] = ok ? y1 + t * (y2 - y1) : 0.0f;
                if (ok) vmask |= 1u << v;
            }
        }

        // masked centroid
        float sxm = 0.0f, sym = 0.0f, nvf = 0.0f;
        #pragma unroll
        for (int v = 0; v < 24; ++v) {
            float mv = ((vmask >> v) & 1u) ? 1.0f : 0.0f;
            nvf += mv; sxm += mv * vx[v]; sym += mv * vy[v];
        }
        float nv = fmaxf(nvf, 1.0f);
        float mx = sxm / nv, my = sym / nv;

        // sort keys: angle for valid, 1e9 for invalid (matches reference)
        #pragma unroll
        for (int v = 0; v < 24; ++v) {
            bool mv = (vmask >> v) & 1u;
            float ang = mv ? atan2f(vy[v] - my, vx[v] - mx) : 1e9f;
            kkey[v] = sortKey(ang);
        }
        #pragma unroll
        for (int v = 24; v < 32; ++v) { kkey[v] = 0xFFFFFFFFu; vx[v] = 0.0f; vy[v] = 0.0f; }

        // bitonic sort, 32 elements, ascending by key (fully unrolled,
        // static indices -> stays in registers)
        #pragma unroll
        for (int kk = 2; kk <= 32; kk <<= 1) {
            #pragma unroll
            for (int j = kk >> 1; j > 0; j >>= 1) {
                #pragma unroll
                for (int t0 = 0; t0 < 32; ++t0) {
                    int o = t0 ^ j;
                    if (o > t0) {
                        bool up = (t0 & kk) == 0;
                        unsigned ka = kkey[t0], kb = kkey[o];
                        bool sw = up ? (ka > kb) : (ka < kb);
                        float xa = vx[t0], xb = vx[o];
                        float ya = vy[t0], yb = vy[o];
                        kkey[t0] = sw ? kb : ka; kkey[o] = sw ? ka : kb;
                        vx[t0]   = sw ? xb : xa; vx[o]   = sw ? xa : xb;
                        vy[t0]   = sw ? yb : ya; vy[o]   = sw ? ya : yb;
                    }
                }
            }
        }

        // shoelace over the first k sorted vertices (equivalent to the
        // reference's where(sm, sv, sv[0]) 24-cyclic shoelace)
        int kcnt = __popc(vmask);
        float area2 = 0.0f;
        #pragma unroll
        for (int v = 0; v < 24; ++v) {
            bool active = (v < kcnt);
            bool wrap = (v + 1 == kcnt);
            float nx2 = wrap ? vx[0] : vx[v + 1];
            float ny2 = wrap ? vy[0] : vy[v + 1];
            float term = vx[v] * ny2 - nx2 * vy[v];
            area2 += active ? term : 0.0f;
        }
        float inter2d = 0.5f * fabsf(area2);

        // z overlap + volumes
        float zmax1 = b1[2] + 0.5f * b1[5], zmin1 = b1[2] - 0.5f * b1[5];
        float zmax2 = b2[2] + 0.5f * b2[5], zmin2 = b2[2] - 0.5f * b2[5];
        float zov = fmaxf(fminf(zmax1, zmax2) - fmaxf(zmin1, zmin2), 0.0f);
        float inter3d = inter2d * zov;
        float vol1 = b1[3] * b1[4] * b1[5];
        float vol2 = b2[3] * b2[4] * b2[5];
        float uni = vol1 + vol2 - inter3d;
        float iou = inter3d / uni;
        float target = iou * 2.0f - 1.0f;

        // diou extras
        float ddx = b1[0] - b2[0], ddy = b1[1] - b2[1], ddz = b1[2] - b2[2];
        float interdiag = ddx * ddx + ddy * ddy + ddz * ddz;
        float outerh = fmaxf(fmaxf(zmax1, zmax2) - fminf(zmin1, zmin2), 0.0f);
        float omx = fmaxf(fmaxf(c1x[2], c2x[2]) - fminf(c1x[0], c2x[0]), 0.0f);
        float omy = fmaxf(fmaxf(c1y[2], c2y[2]) - fminf(c1y[0], c2y[0]), 0.0f);
        float outerdiag = omx * omx + omy * omy + outerh * outerh;
        float diou = iou - interdiag / outerdiag;
        diou = fminf(fmaxf(diou, -1.0f), 1.0f);

        float m = (mask[gid] != 0) ? 1.0f : 0.0f;
        float pred = pred_iou[gid];
        contrib = (fabsf(pred - target) + (1.0f - diou)) * m;
        mfv = m;
    }

    // block reduction: wave shuffle -> LDS -> one atomic pair per block
    #pragma unroll
    for (int off = 32; off > 0; off >>= 1) {
        contrib += __shfl_down(contrib, off, 64);
        mfv     += __shfl_down(mfv, off, 64);
    }
    __shared__ float sC[4], sM[4];
    const int lane = threadIdx.x & 63;
    const int wv = threadIdx.x >> 6;
    if (lane == 0) { sC[wv] = contrib; sM[wv] = mfv; }
    __syncthreads();
    if (threadIdx.x == 0) {
        float tc = sC[0] + sC[1] + sC[2] + sC[3];
        float tm = sM[0] + sM[1] + sM[2] + sM[3];
        atomicAdd(&sums[0], tc);
        atomicAdd(&sums[1], tm);
    }
}

__global__ void finalize_kernel(const float* __restrict__ sums, float* __restrict__ out) {
    if (threadIdx.x == 0 && blockIdx.x == 0)
        out[0] = sums[0] / fmaxf(sums[1], 1e-4f);
}

extern "C" void kernel_launch(void* const* d_in, const int* in_sizes, int n_in,
                              void* d_out, int out_size, void* d_ws, size_t ws_size,
                              hipStream_t stream) {
    const float* pred_iou   = (const float*)d_in[0];
    const float* pred_boxes = (const float*)d_in[1];
    const float* gt_boxes   = (const float*)d_in[2];
    const int*   mask       = (const int*)d_in[3];
    float* out  = (float*)d_out;
    float* sums = (float*)d_ws;
    const int M = in_sizes[0];

    hipMemsetAsync(sums, 0, 2 * sizeof(float), stream);
    const int block = 256;
    const int grid = (M + block - 1) / block;
    hipLaunchKernelGGL(iou3d_loss_kernel, dim3(grid), dim3(block), 0, stream,
                       pred_iou, pred_boxes, gt_boxes, mask, sums, M);
    hipLaunchKernelGGL(finalize_kernel, dim3(1), dim3(64), 0, stream, sums, out);
}

// Round 2
// 134.544 us; speedup vs baseline: 1.0513x; 1.0513x over previous
//
#include <hip/hip_runtime.h>

// IoU3DLoss: per-element rotated 3D IoU (+DIoU) and masked-mean loss.
// One thread per box pair. v2: rank-select compaction (<=8 verts) + bitonic-8,
// pseudo-angle sort keys (no atan2), rcp/rsq instead of divides, hw sincos.

__global__ __launch_bounds__(256, 4) void iou3d_loss_kernel(
    const float* __restrict__ pred_iou,
    const float* __restrict__ pred_boxes,   // [M,7] x,y,z,w,h,l,alpha
    const float* __restrict__ gt_boxes,     // [M,8] x,y,z,w,h,l,sin,cos
    const int*   __restrict__ mask,
    float* __restrict__ sums,               // ws: [0]=contrib sum, [1]=mask count
    int M)
{
    const int gid = blockIdx.x * blockDim.x + threadIdx.x;
    float contrib = 0.0f, mfv = 0.0f;

    if (gid < M) {
        const float* pb = pred_boxes + (size_t)gid * 7;
        const float b1x = pb[0], b1y = pb[1], b1z = pb[2];
        const float b1w = pb[3], b1h = pb[4], b1l = pb[5], a1 = pb[6];
        const float* gb = gt_boxes + (size_t)gid * 8;
        const float b2x = gb[0], b2y = gb[1], b2z = gb[2];
        const float b2w = gb[3], b2h = gb[4], b2l = gb[5];
        const float gsn = gb[6], gcs = gb[7];

        // pred angle: hw sincos; gt angle: cos/sin via rsqrt normalization
        const float sn1 = __sinf(a1), cs1 = __cosf(a1);
        const float rnrm = __builtin_amdgcn_rsqf(gsn * gsn + gcs * gcs);
        const float sn2 = gsn * rnrm, cs2 = gcs * rnrm;

        const float xsg[4] = {0.5f, -0.5f, -0.5f, 0.5f};
        const float ysg[4] = {0.5f, 0.5f, -0.5f, -0.5f};

        float c1x[4], c1y[4], c2x[4], c2y[4];
        #pragma unroll
        for (int k = 0; k < 4; ++k) {
            float xx = xsg[k] * b1w, yy = ysg[k] * b1h;
            c1x[k] = xx * cs1 - yy * sn1 + b1x;
            c1y[k] = xx * sn1 + yy * cs1 + b1y;
            float x2 = xsg[k] * b2w, y2 = ysg[k] * b2h;
            c2x[k] = x2 * cs2 - y2 * sn2 + b2x;
            c2y[k] = x2 * sn2 + y2 * cs2 + b2y;
        }

        // candidates 0-3: c1 corners, 4-7: c2 corners, 8-23: edge crossings
        float vx[24], vy[24];
        unsigned vmask = 0u;
        const float eps = 1e-6f;

        {   // c1 corners inside box2 (multiplied-through comparisons, no div)
            float ax = c2x[0], ay = c2y[0];
            float abx = c2x[1] - ax, aby = c2y[1] - ay;
            float adx = c2x[3] - ax, ady = c2y[3] - ay;
            float ab2 = abx * abx + aby * aby;
            float ad2 = adx * adx + ady * ady;
            float lo_ab = -eps * ab2, hi_ab = (1.0f + eps) * ab2;
            float lo_ad = -eps * ad2, hi_ad = (1.0f + eps) * ad2;
            #pragma unroll
            for (int k = 0; k < 4; ++k) {
                vx[k] = c1x[k]; vy[k] = c1y[k];
                float apx = c1x[k] - ax, apy = c1y[k] - ay;
                float dab = apx * abx + apy * aby;
                float dad = apx * adx + apy * ady;
                bool in2 = (dab > lo_ab) && (dab < hi_ab) && (dad > lo_ad) && (dad < hi_ad);
                vmask |= (in2 ? 1u : 0u) << k;
            }
        }
        {   // c2 corners inside box1
            float ax = c1x[0], ay = c1y[0];
            float abx = c1x[1] - ax, aby = c1y[1] - ay;
            float adx = c1x[3] - ax, ady = c1y[3] - ay;
            float ab2 = abx * abx + aby * aby;
            float ad2 = adx * adx + ady * ady;
            float lo_ab = -eps * ab2, hi_ab = (1.0f + eps) * ab2;
            float lo_ad = -eps * ad2, hi_ad = (1.0f + eps) * ad2;
            #pragma unroll
            for (int k = 0; k < 4; ++k) {
                vx[4 + k] = c2x[k]; vy[4 + k] = c2y[k];
                float apx = c2x[k] - ax, apy = c2y[k] - ay;
                float dab = apx * abx + apy * aby;
                float dad = apx * adx + apy * ady;
                bool in1 = (dab > lo_ab) && (dab < hi_ab) && (dad > lo_ad) && (dad < hi_ad);
                vmask |= (in1 ? 1u : 0u) << (4 + k);
            }
        }

        // edge-of-box1 x edge-of-box2 crossings; rcp instead of guarded divide
        // (den==0 -> inf/NaN t,u -> all comparisons false, same as reference)
        float e1dx[4], e1dy[4], e2dx[4], e2dy[4];
        #pragma unroll
        for (int l = 0; l < 4; ++l) {
            e1dx[l] = c1x[l] - c1x[(l + 1) & 3];   // x1 - x2
            e1dy[l] = c1y[l] - c1y[(l + 1) & 3];
            e2dx[l] = c2x[l] - c2x[(l + 1) & 3];   // x3 - x4
            e2dy[l] = c2y[l] - c2y[(l + 1) & 3];
        }
        #pragma unroll
        for (int l = 0; l < 4; ++l) {
            float x1 = c1x[l], y1 = c1y[l];
            #pragma unroll
            for (int m = 0; m < 4; ++m) {
                float rx = x1 - c2x[m], ry = y1 - c2y[m];       // x1-x3, y1-y3
                float den  = e1dx[l] * e2dy[m] - e2dx[m] * e1dy[l];
                float numt = e2dx[m] * ry - e2dy[m] * rx;
                float numu = e1dx[l] * ry - e1dy[l] * rx;
                float rden = __builtin_amdgcn_rcpf(den);
                float t = numt * rden;
                float u = -(numu * rden);
                bool ok = (t > 0.0f) && (t < 1.0f) && (u > 0.0f) && (u < 1.0f);
                int v = 8 + l * 4 + m;
                vx[v] = x1 - t * e1dx[l];
                vy[v] = y1 - t * e1dy[l];
                vmask |= (ok ? 1u : 0u) << v;
            }
        }

        // masked centroid over all 24 candidates (select, not multiply:
        // invalid slots may hold inf/NaN)
        float sxm = 0.0f, sym = 0.0f;
        #pragma unroll
        for (int v = 0; v < 24; ++v) {
            bool mv = (vmask >> v) & 1u;
            sxm += mv ? vx[v] : 0.0f;
            sym += mv ? vy[v] : 0.0f;
        }
        float nvf = (float)__popc(vmask);
        float rnv = __builtin_amdgcn_rcpf(fmaxf(nvf, 1.0f));
        float mx = sxm * rnv, my = sym * rnv;

        // rank-select compaction of valid candidates into 8 slots
        float px[8], py[8];
        #pragma unroll
        for (int j = 0; j < 8; ++j) { px[j] = 0.0f; py[j] = 0.0f; }
        #pragma unroll
        for (int v = 0; v < 24; ++v) {
            bool valid = (vmask >> v) & 1u;
            unsigned r = (unsigned)__popc(vmask & ((1u << v) - 1u));
            #pragma unroll
            for (int j = 0; j < 8; ++j) {
                bool take = valid && (r == (unsigned)j);
                px[j] = take ? vx[v] : px[j];
                py[j] = take ? vy[v] : py[j];
            }
        }
        int kcnt = __popc(vmask);
        if (kcnt > 8) kcnt = 8;   // >8 only in eps-degenerate configs

        // pseudo-angle keys (diamond angle: monotone in atan2 -> same order)
        float key[8];
        #pragma unroll
        for (int j = 0; j < 8; ++j) {
            float dx = px[j] - mx, dy = py[j] - my;
            float ad = fabsf(dx) + fabsf(dy);
            float r = dx * __builtin_amdgcn_rcpf(fmaxf(ad, 1e-30f));
            float k = __builtin_copysignf(1.0f - r, dy);
            key[j] = (j < kcnt) ? k : 1e9f;
        }

        // bitonic-8 ascending by key, payload (px,py)
        #pragma unroll
        for (int kk = 2; kk <= 8; kk <<= 1) {
            #pragma unroll
            for (int j = kk >> 1; j > 0; j >>= 1) {
                #pragma unroll
                for (int t0 = 0; t0 < 8; ++t0) {
                    int o = t0 ^ j;
                    if (o > t0) {
                        bool up = (t0 & kk) == 0;
                        float ka = key[t0], kb = key[o];
                        bool sw = up ? (ka > kb) : (ka < kb);
                        float xa = px[t0], xb = px[o];
                        float ya = py[t0], yb = py[o];
                        key[t0] = sw ? kb : ka; key[o] = sw ? ka : kb;
                        px[t0]  = sw ? xb : xa; px[o]  = sw ? xa : xb;
                        py[t0]  = sw ? yb : ya; py[o]  = sw ? ya : yb;
                    }
                }
            }
        }

        // shoelace over first kcnt sorted vertices (== reference's
        // where(sm, sv, sv[0]) cyclic shoelace)
        float x0 = px[0], y0 = py[0];
        float area2 = 0.0f;
        #pragma unroll
        for (int v = 0; v < 8; ++v) {
            bool active = (v < kcnt);
            bool wrap = (v + 1 == kcnt);
            float nx2 = (v == 7) ? x0 : (wrap ? x0 : px[v + 1]);
            float ny2 = (v == 7) ? y0 : (wrap ? y0 : py[v + 1]);
            float term = px[v] * ny2 - nx2 * py[v];
            area2 += active ? term : 0.0f;
        }
        float inter2d = 0.5f * fabsf(area2);

        // z overlap + volumes
        float zmax1 = b1z + 0.5f * b1l, zmin1 = b1z - 0.5f * b1l;
        float zmax2 = b2z + 0.5f * b2l, zmin2 = b2z - 0.5f * b2l;
        float zov = fmaxf(fminf(zmax1, zmax2) - fmaxf(zmin1, zmin2), 0.0f);
        float inter3d = inter2d * zov;
        float vol1 = b1w * b1h * b1l;
        float vol2 = b2w * b2h * b2l;
        float uni = vol1 + vol2 - inter3d;
        float iou = inter3d * __builtin_amdgcn_rcpf(uni);
        float target = iou * 2.0f - 1.0f;

        // diou extras
        float ddx = b1x - b2x, ddy = b1y - b2y, ddz = b1z - b2z;
        float interdiag = ddx * ddx + ddy * ddy + ddz * ddz;
        float outerh = fmaxf(fmaxf(zmax1, zmax2) - fminf(zmin1, zmin2), 0.0f);
        float omx = fmaxf(fmaxf(c1x[2], c2x[2]) - fminf(c1x[0], c2x[0]), 0.0f);
        float omy = fmaxf(fmaxf(c1y[2], c2y[2]) - fminf(c1y[0], c2y[0]), 0.0f);
        float outerdiag = omx * omx + omy * omy + outerh * outerh;
        float diou = iou - interdiag * __builtin_amdgcn_rcpf(outerdiag);
        diou = fminf(fmaxf(diou, -1.0f), 1.0f);

        float m = (mask[gid] != 0) ? 1.0f : 0.0f;
        float pred = pred_iou[gid];
        contrib = (fabsf(pred - target) + (1.0f - diou)) * m;
        mfv = m;
    }

    // block reduction: wave shuffle -> LDS -> one atomic pair per block
    #pragma unroll
    for (int off = 32; off > 0; off >>= 1) {
        contrib += __shfl_down(contrib, off, 64);
        mfv     += __shfl_down(mfv, off, 64);
    }
    __shared__ float sC[4], sM[4];
    const int lane = threadIdx.x & 63;
    const int wv = threadIdx.x >> 6;
    if (lane == 0) { sC[wv] = contrib; sM[wv] = mfv; }
    __syncthreads();
    if (threadIdx.x == 0) {
        float tc = sC[0] + sC[1] + sC[2] + sC[3];
        float tm = sM[0] + sM[1] + sM[2] + sM[3];
        atomicAdd(&sums[0], tc);
        atomicAdd(&sums[1], tm);
    }
}

__global__ void finalize_kernel(const float* __restrict__ sums, float* __restrict__ out) {
    if (threadIdx.x == 0 && blockIdx.x == 0)
        out[0] = sums[0] / fmaxf(sums[1], 1e-4f);
}

extern "C" void kernel_launch(void* const* d_in, const int* in_sizes, int n_in,
                              void* d_out, int out_size, void* d_ws, size_t ws_size,
                              hipStream_t stream) {
    const float* pred_iou   = (const float*)d_in[0];
    const float* pred_boxes = (const float*)d_in[1];
    const float* gt_boxes   = (const float*)d_in[2];
    const int*   mask       = (const int*)d_in[3];
    float* out  = (float*)d_out;
    float* sums = (float*)d_ws;
    const int M = in_sizes[0];

    hipMemsetAsync(sums, 0, 2 * sizeof(float), stream);
    const int block = 256;
    const int grid = (M + block - 1) / block;
    hipLaunchKernelGGL(iou3d_loss_kernel, dim3(grid), dim3(block), 0, stream,
                       pred_iou, pred_boxes, gt_boxes, mask, sums, M);
    hipLaunchKernelGGL(finalize_kernel, dim3(1), dim3(64), 0, stream, sums, out);
}

// Round 3
// 113.075 us; speedup vs baseline: 1.2509x; 1.1899x over previous
//
#include <hip/hip_runtime.h>

// IoU3DLoss: per-element rotated 3D IoU (+DIoU) and masked-mean loss.
// v3: u-sign fix (round-2 bug), 2 elements/thread for cross-element ILP,
// leaner compaction (incremental rank, no valid-guard, triangular slots).

#define RCPF(x) __builtin_amdgcn_rcpf(x)

struct EIn {
    float b[7];   // pred box: x,y,z,w,h,l,alpha
    float g[8];   // gt box:   x,y,z,w,h,l,sin,cos
    float pred;
    float mf;
};

__device__ __forceinline__ void load_elem(EIn& e,
    const float* __restrict__ pred_iou, const float* __restrict__ pred_boxes,
    const float* __restrict__ gt_boxes, const int* __restrict__ mask, int gid)
{
    const float* pb = pred_boxes + (size_t)gid * 7;
    #pragma unroll
    for (int k = 0; k < 7; ++k) e.b[k] = pb[k];
    const float* gb = gt_boxes + (size_t)gid * 8;
    #pragma unroll
    for (int k = 0; k < 8; ++k) e.g[k] = gb[k];
    e.pred = pred_iou[gid];
    e.mf = (mask[gid] != 0) ? 1.0f : 0.0f;
}

__device__ __forceinline__ float elem_body(const EIn& e)
{
    const float b1x = e.b[0], b1y = e.b[1], b1z = e.b[2];
    const float b1w = e.b[3], b1h = e.b[4], b1l = e.b[5], a1 = e.b[6];
    const float b2x = e.g[0], b2y = e.g[1], b2z = e.g[2];
    const float b2w = e.g[3], b2h = e.g[4], b2l = e.g[5];
    const float gsn = e.g[6], gcs = e.g[7];

    float sn1, cs1;
    __sincosf(a1, &sn1, &cs1);
    const float rn = __builtin_amdgcn_rsqf(gsn * gsn + gcs * gcs);
    const float sn2 = gsn * rn, cs2 = gcs * rn;

    const float xs[4] = {0.5f, -0.5f, -0.5f, 0.5f};
    const float ys[4] = {0.5f, 0.5f, -0.5f, -0.5f};
    float c1x[4], c1y[4], c2x[4], c2y[4];
    #pragma unroll
    for (int k = 0; k < 4; ++k) {
        float xx = xs[k] * b1w, yy = ys[k] * b1h;
        c1x[k] = xx * cs1 - yy * sn1 + b1x;
        c1y[k] = xx * sn1 + yy * cs1 + b1y;
        float x2 = xs[k] * b2w, y2 = ys[k] * b2h;
        c2x[k] = x2 * cs2 - y2 * sn2 + b2x;
        c2y[k] = x2 * sn2 + y2 * cs2 + b2y;
    }

    // candidates 0-3: c1 corners, 4-7: c2 corners, 8-23: edge crossings
    float vx[24], vy[24];
    unsigned vmask = 0u;
    const float eps = 1e-6f;

    {   // c1 corners inside box2 (multiplied-through comparisons)
        float ax = c2x[0], ay = c2y[0];
        float abx = c2x[1] - ax, aby = c2y[1] - ay;
        float adx = c2x[3] - ax, ady = c2y[3] - ay;
        float ab2 = abx * abx + aby * aby;
        float ad2 = adx * adx + ady * ady;
        float lo_ab = -eps * ab2, hi_ab = (1.0f + eps) * ab2;
        float lo_ad = -eps * ad2, hi_ad = (1.0f + eps) * ad2;
        #pragma unroll
        for (int k = 0; k < 4; ++k) {
            vx[k] = c1x[k]; vy[k] = c1y[k];
            float apx = c1x[k] - ax, apy = c1y[k] - ay;
            float dab = apx * abx + apy * aby;
            float dad = apx * adx + apy * ady;
            bool in2 = (dab > lo_ab) && (dab < hi_ab) && (dad > lo_ad) && (dad < hi_ad);
            vmask |= (in2 ? 1u : 0u) << k;
        }
    }
    {   // c2 corners inside box1
        float ax = c1x[0], ay = c1y[0];
        float abx = c1x[1] - ax, aby = c1y[1] - ay;
        float adx = c1x[3] - ax, ady = c1y[3] - ay;
        float ab2 = abx * abx + aby * aby;
        float ad2 = adx * adx + ady * ady;
        float lo_ab = -eps * ab2, hi_ab = (1.0f + eps) * ab2;
        float lo_ad = -eps * ad2, hi_ad = (1.0f + eps) * ad2;
        #pragma unroll
        for (int k = 0; k < 4; ++k) {
            vx[4 + k] = c2x[k]; vy[4 + k] = c2y[k];
            float apx = c2x[k] - ax, apy = c2y[k] - ay;
            float dab = apx * abx + apy * aby;
            float dad = apx * adx + apy * ady;
            bool in1 = (dab > lo_ab) && (dab < hi_ab) && (dad > lo_ad) && (dad < hi_ad);
            vmask |= (in1 ? 1u : 0u) << (4 + k);
        }
    }

    // edge crossings; reference semantics: t = num_t/den, u = -num_u/den,
    // den==0 -> reject (rcp -> inf/NaN -> comparisons false).
    float e1dx[4], e1dy[4], e2dx[4], e2dy[4];
    #pragma unroll
    for (int l = 0; l < 4; ++l) {
        e1dx[l] = c1x[l] - c1x[(l + 1) & 3];   // x1 - x2
        e1dy[l] = c1y[l] - c1y[(l + 1) & 3];
        e2dx[l] = c2x[l] - c2x[(l + 1) & 3];   // x3 - x4
        e2dy[l] = c2y[l] - c2y[(l + 1) & 3];
    }
    #pragma unroll
    for (int l = 0; l < 4; ++l) {
        float x1 = c1x[l], y1 = c1y[l];
        #pragma unroll
        for (int m = 0; m < 4; ++m) {
            float rx = x1 - c2x[m], ry = y1 - c2y[m];       // x1-x3, y1-y3
            float den  = e1dx[l] * e2dy[m] - e2dx[m] * e1dy[l];   // == den_ref
            float numt = e2dx[m] * ry - e2dy[m] * rx;             // == num_t_ref
            float numu = e1dx[l] * ry - e1dy[l] * rx;             // == -num_u_ref
            float rden = RCPF(den);
            float t = numt * rden;            // t_ref
            float u = numu * rden;            // -num_u_ref/den == u_ref  (v3 FIX)
            bool ok = (t > 0.0f) && (t < 1.0f) && (u > 0.0f) && (u < 1.0f);
            int v = 8 + l * 4 + m;
            vx[v] = x1 - t * e1dx[l];
            vy[v] = y1 - t * e1dy[l];
            vmask |= (ok ? 1u : 0u) << v;
        }
    }

    // rank-select compaction into 8 slots.
    // r = exclusive prefix-popcount. No validity guard needed: for any slot
    // j < kcnt the LAST candidate with r==j is exactly the valid rank-j one
    // (candidates after it have rank j+1); slots >= kcnt hold garbage but are
    // masked out everywhere below.
    float px[8], py[8];
    #pragma unroll
    for (int j = 0; j < 8; ++j) { px[j] = 0.0f; py[j] = 0.0f; }
    unsigned r = 0u;
    #pragma unroll
    for (int v = 0; v < 24; ++v) {
        #pragma unroll
        for (int j = 0; j < 8; ++j) {
            if (j <= v) {
                bool take = (r == (unsigned)j);
                px[j] = take ? vx[v] : px[j];
                py[j] = take ? vy[v] : py[j];
            }
        }
        r += (vmask >> v) & 1u;
    }
    int kcnt = (int)r;
    if (kcnt > 8) kcnt = 8;   // >8 only in eps-degenerate configs

    // centroid from compacted slots
    float sxm = 0.0f, sym = 0.0f;
    #pragma unroll
    for (int j = 0; j < 8; ++j) {
        bool a = (j < kcnt);
        sxm += a ? px[j] : 0.0f;
        sym += a ? py[j] : 0.0f;
    }
    float rnv = RCPF(fmaxf((float)kcnt, 1.0f));
    float mx = sxm * rnv, my = sym * rnv;

    // pseudo-angle keys (diamond angle: same cyclic order as atan2)
    float key[8];
    #pragma unroll
    for (int j = 0; j < 8; ++j) {
        float dx = px[j] - mx, dy = py[j] - my;
        float ad = fabsf(dx) + fabsf(dy);
        float rr = dx * RCPF(fmaxf(ad, 1e-30f));
        float k = __builtin_copysignf(1.0f - rr, dy);
        key[j] = (j < kcnt) ? k : 1e9f;
    }

    // bitonic-8 ascending by key, payload (px,py)
    #pragma unroll
    for (int kk = 2; kk <= 8; kk <<= 1) {
        #pragma unroll
        for (int j = kk >> 1; j > 0; j >>= 1) {
            #pragma unroll
            for (int t0 = 0; t0 < 8; ++t0) {
                int o = t0 ^ j;
                if (o > t0) {
                    bool up = (t0 & kk) == 0;
                    float ka = key[t0], kb = key[o];
                    bool sw = up ? (ka > kb) : (ka < kb);
                    float xa = px[t0], xb = px[o];
                    float ya = py[t0], yb = py[o];
                    key[t0] = sw ? kb : ka; key[o] = sw ? ka : kb;
                    px[t0]  = sw ? xb : xa; px[o]  = sw ? xa : xb;
                    py[t0]  = sw ? yb : ya; py[o]  = sw ? ya : yb;
                }
            }
        }
    }

    // shoelace over first kcnt sorted vertices (== reference's cyclic form)
    float x0 = px[0], y0 = py[0];
    float area2 = 0.0f;
    #pragma unroll
    for (int v = 0; v < 8; ++v) {
        bool active = (v < kcnt);
        bool wrap = (v + 1 == kcnt);
        float nx2 = (v == 7) ? x0 : (wrap ? x0 : px[v + 1]);
        float ny2 = (v == 7) ? y0 : (wrap ? y0 : py[v + 1]);
        float term = px[v] * ny2 - nx2 * py[v];
        area2 += active ? term : 0.0f;
    }
    float inter2d = 0.5f * fabsf(area2);

    // z overlap + volumes
    float zmax1 = b1z + 0.5f * b1l, zmin1 = b1z - 0.5f * b1l;
    float zmax2 = b2z + 0.5f * b2l, zmin2 = b2z - 0.5f * b2l;
    float zov = fmaxf(fminf(zmax1, zmax2) - fmaxf(zmin1, zmin2), 0.0f);
    float inter3d = inter2d * zov;
    float vol1 = b1w * b1h * b1l;
    float vol2 = b2w * b2h * b2l;
    float uni = vol1 + vol2 - inter3d;
    float iou = inter3d * RCPF(uni);
    float target = iou * 2.0f - 1.0f;

    // diou extras
    float ddx = b1x - b2x, ddy = b1y - b2y, ddz = b1z - b2z;
    float interdiag = ddx * ddx + ddy * ddy + ddz * ddz;
    float outerh = fmaxf(fmaxf(zmax1, zmax2) - fminf(zmin1, zmin2), 0.0f);
    float omx = fmaxf(fmaxf(c1x[2], c2x[2]) - fminf(c1x[0], c2x[0]), 0.0f);
    float omy = fmaxf(fmaxf(c1y[2], c2y[2]) - fminf(c1y[0], c2y[0]), 0.0f);
    float outerdiag = omx * omx + omy * omy + outerh * outerh;
    float diou = iou - interdiag * RCPF(outerdiag);
    diou = fminf(fmaxf(diou, -1.0f), 1.0f);

    return (fabsf(e.pred - target) + (1.0f - diou)) * e.mf;
}

__global__ __launch_bounds__(256, 4) void iou3d_loss_kernel(
    const float* __restrict__ pred_iou,
    const float* __restrict__ pred_boxes,
    const float* __restrict__ gt_boxes,
    const int*   __restrict__ mask,
    float* __restrict__ sums,
    int M)
{
    const int idx0 = blockIdx.x * blockDim.x + threadIdx.x;
    const int stride = gridDim.x * blockDim.x;
    const int idx1 = idx0 + stride;

    float contrib = 0.0f, mfv = 0.0f;

    if (idx1 < M) {
        // hot path: both elements in ONE basic block -> scheduler can
        // interleave the two independent dependency chains
        EIn e0, e1;
        load_elem(e0, pred_iou, pred_boxes, gt_boxes, mask, idx0);
        load_elem(e1, pred_iou, pred_boxes, gt_boxes, mask, idx1);
        contrib = elem_body(e0) + elem_body(e1);
        mfv = e0.mf + e1.mf;
    } else if (idx0 < M) {
        EIn e0;
        load_elem(e0, pred_iou, pred_boxes, gt_boxes, mask, idx0);
        contrib = elem_body(e0);
        mfv = e0.mf;
    }

    // block reduction: wave shuffle -> LDS -> one atomic pair per block
    #pragma unroll
    for (int off = 32; off > 0; off >>= 1) {
        contrib += __shfl_down(contrib, off, 64);
        mfv     += __shfl_down(mfv, off, 64);
    }
    __shared__ float sC[4], sM[4];
    const int lane = threadIdx.x & 63;
    const int wv = threadIdx.x >> 6;
    if (lane == 0) { sC[wv] = contrib; sM[wv] = mfv; }
    __syncthreads();
    if (threadIdx.x == 0) {
        float tc = sC[0] + sC[1] + sC[2] + sC[3];
        float tm = sM[0] + sM[1] + sM[2] + sM[3];
        atomicAdd(&sums[0], tc);
        atomicAdd(&sums[1], tm);
    }
}

__global__ void finalize_kernel(const float* __restrict__ sums, float* __restrict__ out) {
    if (threadIdx.x == 0 && blockIdx.x == 0)
        out[0] = sums[0] / fmaxf(sums[1], 1e-4f);
}

extern "C" void kernel_launch(void* const* d_in, const int* in_sizes, int n_in,
                              void* d_out, int out_size, void* d_ws, size_t ws_size,
                              hipStream_t stream) {
    const float* pred_iou   = (const float*)d_in[0];
    const float* pred_boxes = (const float*)d_in[1];
    const float* gt_boxes   = (const float*)d_in[2];
    const int*   mask       = (const int*)d_in[3];
    float* out  = (float*)d_out;
    float* sums = (float*)d_ws;
    const int M = in_sizes[0];

    hipMemsetAsync(sums, 0, 2 * sizeof(float), stream);
    const int block = 256;
    const int elems_per_thread = 2;
    int grid = (M + block * elems_per_thread - 1) / (block * elems_per_thread);
    if (grid < 1) grid = 1;
    hipLaunchKernelGGL(iou3d_loss_kernel, dim3(grid), dim3(block), 0, stream,
                       pred_iou, pred_boxes, gt_boxes, mask, sums, M);
    hipLaunchKernelGGL(finalize_kernel, dim3(1), dim3(64), 0, stream, sums, out);
}

// Round 4
// 112.121 us; speedup vs baseline: 1.2615x; 1.0085x over previous
//
#include <hip/hip_runtime.h>

// IoU3DLoss: per-element rotated 3D IoU (+DIoU) and masked-mean loss.
// v4: LDS rank-scatter compaction (replaces ~490 VALU cndmask chains with
// 24 ds_write_b64), division-free crossing masks, single straight-line path.

#define RCPF(x) __builtin_amdgcn_rcpf(x)

struct EIn {
    float b[7];   // pred box: x,y,z,w,h,l,alpha
    float g[8];   // gt box:   x,y,z,w,h,l,sin,cos
    float pred;
    float mf;
};

__device__ __forceinline__ void load_elem(EIn& e,
    const float* __restrict__ pred_iou, const float* __restrict__ pred_boxes,
    const float* __restrict__ gt_boxes, const int* __restrict__ mask,
    int gid, bool active)
{
    const float* pb = pred_boxes + (size_t)gid * 7;
    #pragma unroll
    for (int k = 0; k < 7; ++k) e.b[k] = pb[k];
    const float* gb = gt_boxes + (size_t)gid * 8;
    #pragma unroll
    for (int k = 0; k < 8; ++k) e.g[k] = gb[k];
    e.pred = pred_iou[gid];
    e.mf = (active && mask[gid] != 0) ? 1.0f : 0.0f;
}

// sl: this element's private LDS region, 18 words (9 float2 slots:
// 8 rank slots + 1 sacrificial overflow slot). 8B-aligned.
__device__ __forceinline__ float elem_body(const EIn& e, float* __restrict__ sl)
{
    const float b1x = e.b[0], b1y = e.b[1], b1z = e.b[2];
    const float b1w = e.b[3], b1h = e.b[4], b1l = e.b[5], a1 = e.b[6];
    const float b2x = e.g[0], b2y = e.g[1], b2z = e.g[2];
    const float b2w = e.g[3], b2h = e.g[4], b2l = e.g[5];
    const float gsn = e.g[6], gcs = e.g[7];

    float sn1, cs1;
    __sincosf(a1, &sn1, &cs1);
    const float rn = __builtin_amdgcn_rsqf(gsn * gsn + gcs * gcs);
    const float sn2 = gsn * rn, cs2 = gcs * rn;

    const float xs[4] = {0.5f, -0.5f, -0.5f, 0.5f};
    const float ys[4] = {0.5f, 0.5f, -0.5f, -0.5f};
    float c1x[4], c1y[4], c2x[4], c2y[4];
    #pragma unroll
    for (int k = 0; k < 4; ++k) {
        float xx = xs[k] * b1w, yy = ys[k] * b1h;
        c1x[k] = xx * cs1 - yy * sn1 + b1x;
        c1y[k] = xx * sn1 + yy * cs1 + b1y;
        float x2 = xs[k] * b2w, y2 = ys[k] * b2h;
        c2x[k] = x2 * cs2 - y2 * sn2 + b2x;
        c2y[k] = x2 * sn2 + y2 * cs2 + b2y;
    }

    float2* slot = reinterpret_cast<float2*>(sl);
    unsigned r = 0u;   // running rank = count of valid candidates so far

    // Streaming rank-scatter: write candidate to slot min(r,8) ALWAYS.
    // An invalid candidate writes slot r, which no valid candidate has
    // claimed yet; a later valid rank-r candidate overwrites it. Slots
    // >= final count hold garbage and are masked out downstream.
    const float eps = 1e-6f;

    {   // candidates 0-3: c1 corners, valid if inside box2
        float ax = c2x[0], ay = c2y[0];
        float abx = c2x[1] - ax, aby = c2y[1] - ay;
        float adx = c2x[3] - ax, ady = c2y[3] - ay;
        float ab2 = abx * abx + aby * aby;
        float ad2 = adx * adx + ady * ady;
        float lo_ab = -eps * ab2, hi_ab = (1.0f + eps) * ab2;
        float lo_ad = -eps * ad2, hi_ad = (1.0f + eps) * ad2;
        #pragma unroll
        for (int k = 0; k < 4; ++k) {
            float apx = c1x[k] - ax, apy = c1y[k] - ay;
            float dab = apx * abx + apy * aby;
            float dad = apx * adx + apy * ady;
            bool ok = (dab > lo_ab) && (dab < hi_ab) && (dad > lo_ad) && (dad < hi_ad);
            unsigned rm = r < 8u ? r : 8u;
            slot[rm] = make_float2(c1x[k], c1y[k]);
            r += ok ? 1u : 0u;
        }
    }
    {   // candidates 4-7: c2 corners, valid if inside box1
        float ax = c1x[0], ay = c1y[0];
        float abx = c1x[1] - ax, aby = c1y[1] - ay;
        float adx = c1x[3] - ax, ady = c1y[3] - ay;
        float ab2 = abx * abx + aby * aby;
        float ad2 = adx * adx + ady * ady;
        float lo_ab = -eps * ab2, hi_ab = (1.0f + eps) * ab2;
        float lo_ad = -eps * ad2, hi_ad = (1.0f + eps) * ad2;
        #pragma unroll
        for (int k = 0; k < 4; ++k) {
            float apx = c2x[k] - ax, apy = c2y[k] - ay;
            float dab = apx * abx + apy * aby;
            float dad = apx * adx + apy * ady;
            bool ok = (dab > lo_ab) && (dab < hi_ab) && (dad > lo_ad) && (dad < hi_ad);
            unsigned rm = r < 8u ? r : 8u;
            slot[rm] = make_float2(c2x[k], c2y[k]);
            r += ok ? 1u : 0u;
        }
    }

    // candidates 8-23: edge crossings (reference's phantom semantics,
    // verified bit-matching in rounds 1/3). Mask via sign/magnitude tests
    // (no rcp on the mask path); rcp only for the point coordinates.
    float e1dx[4], e1dy[4], e2dx[4], e2dy[4];
    #pragma unroll
    for (int l = 0; l < 4; ++l) {
        e1dx[l] = c1x[l] - c1x[(l + 1) & 3];   // x1 - x2
        e1dy[l] = c1y[l] - c1y[(l + 1) & 3];
        e2dx[l] = c2x[l] - c2x[(l + 1) & 3];   // x3 - x4
        e2dy[l] = c2y[l] - c2y[(l + 1) & 3];
    }
    #pragma unroll
    for (int l = 0; l < 4; ++l) {
        float x1 = c1x[l], y1 = c1y[l];
        #pragma unroll
        for (int m = 0; m < 4; ++m) {
            float rx = x1 - c2x[m], ry = y1 - c2y[m];
            float den  = e1dx[l] * e2dy[m] - e2dx[m] * e1dy[l];
            float numt = e2dx[m] * ry - e2dy[m] * rx;
            float numu = e1dx[l] * ry - e1dy[l] * rx;
            // t = numt/den in (0,1)  <=>  numt*den>0 && |numt|<|den|
            // u = numu/den in (0,1)  <=>  numu*den>0 && |numu|<|den|
            // den==0 -> products are 0 -> rejected (matches reference)
            float aden = fabsf(den);
            bool ok = (numt * den > 0.0f) && (fabsf(numt) < aden) &&
                      (numu * den > 0.0f) && (fabsf(numu) < aden);
            float t = numt * RCPF(den);
            float X = x1 - t * e1dx[l];
            float Y = y1 - t * e1dy[l];
            unsigned rm = r < 8u ? r : 8u;
            slot[rm] = make_float2(X, Y);
            r += ok ? 1u : 0u;
        }
    }

    // read back compacted slots (static offsets)
    float px[8], py[8];
    #pragma unroll
    for (int j = 0; j < 8; ++j) {
        float2 p = slot[j];
        px[j] = p.x; py[j] = p.y;
    }
    int kcnt = (int)(r < 8u ? r : 8u);

    // centroid over valid slots (select, not multiply: garbage slots)
    float sxm = 0.0f, sym = 0.0f;
    #pragma unroll
    for (int j = 0; j < 8; ++j) {
        bool a = (j < kcnt);
        sxm += a ? px[j] : 0.0f;
        sym += a ? py[j] : 0.0f;
    }
    float rnv = RCPF(fmaxf((float)kcnt, 1.0f));
    float mx = sxm * rnv, my = sym * rnv;

    // pseudo-angle keys (diamond angle: same cyclic order as atan2)
    float key[8];
    #pragma unroll
    for (int j = 0; j < 8; ++j) {
        float dx = px[j] - mx, dy = py[j] - my;
        float ad = fabsf(dx) + fabsf(dy);
        float rr = dx * RCPF(fmaxf(ad, 1e-30f));
        float k = __builtin_copysignf(1.0f - rr, dy);
        key[j] = (j < kcnt) ? k : 1e9f;
    }

    // bitonic-8 ascending by key, payload (px,py)
    #pragma unroll
    for (int kk = 2; kk <= 8; kk <<= 1) {
        #pragma unroll
        for (int j = kk >> 1; j > 0; j >>= 1) {
            #pragma unroll
            for (int t0 = 0; t0 < 8; ++t0) {
                int o = t0 ^ j;
                if (o > t0) {
                    bool up = (t0 & kk) == 0;
                    float ka = key[t0], kb = key[o];
                    bool sw = up ? (ka > kb) : (ka < kb);
                    float xa = px[t0], xb = px[o];
                    float ya = py[t0], yb = py[o];
                    key[t0] = sw ? kb : ka; key[o] = sw ? ka : kb;
                    px[t0]  = sw ? xb : xa; px[o]  = sw ? xa : xb;
                    py[t0]  = sw ? yb : ya; py[o]  = sw ? ya : yb;
                }
            }
        }
    }

    // shoelace over first kcnt sorted vertices (== reference's cyclic form)
    float x0 = px[0], y0 = py[0];
    float area2 = 0.0f;
    #pragma unroll
    for (int v = 0; v < 8; ++v) {
        bool active = (v < kcnt);
        bool wrap = (v + 1 == kcnt);
        float nx2 = (v == 7) ? x0 : (wrap ? x0 : px[v + 1]);
        float ny2 = (v == 7) ? y0 : (wrap ? y0 : py[v + 1]);
        float term = px[v] * ny2 - nx2 * py[v];
        area2 += active ? term : 0.0f;
    }
    float inter2d = 0.5f * fabsf(area2);

    // z overlap + volumes
    float zmax1 = b1z + 0.5f * b1l, zmin1 = b1z - 0.5f * b1l;
    float zmax2 = b2z + 0.5f * b2l, zmin2 = b2z - 0.5f * b2l;
    float zov = fmaxf(fminf(zmax1, zmax2) - fmaxf(zmin1, zmin2), 0.0f);
    float inter3d = inter2d * zov;
    float vol1 = b1w * b1h * b1l;
    float vol2 = b2w * b2h * b2l;
    float uni = vol1 + vol2 - inter3d;
    float iou = inter3d * RCPF(uni);
    float target = iou * 2.0f - 1.0f;

    // diou extras
    float ddx = b1x - b2x, ddy = b1y - b2y, ddz = b1z - b2z;
    float interdiag = ddx * ddx + ddy * ddy + ddz * ddz;
    float outerh = fmaxf(fmaxf(zmax1, zmax2) - fminf(zmin1, zmin2), 0.0f);
    float omx = fmaxf(fmaxf(c1x[2], c2x[2]) - fminf(c1x[0], c2x[0]), 0.0f);
    float omy = fmaxf(fmaxf(c1y[2], c2y[2]) - fminf(c1y[0], c2y[0]), 0.0f);
    float outerdiag = omx * omx + omy * omy + outerh * outerh;
    float diou = iou - interdiag * RCPF(outerdiag);
    diou = fminf(fmaxf(diou, -1.0f), 1.0f);

    return (fabsf(e.pred - target) + (1.0f - diou)) * e.mf;
}

__global__ __launch_bounds__(256, 4) void iou3d_loss_kernel(
    const float* __restrict__ pred_iou,
    const float* __restrict__ pred_boxes,
    const float* __restrict__ gt_boxes,
    const int*   __restrict__ mask,
    float* __restrict__ sums,
    int M)
{
    // 38 words (152 B) per thread: elem0 slots words 0..17, elem1 18..35,
    // 2 pad words. Word stride 38 (== 6 mod 32) -> uniform bank spread
    // (4 lanes/bank = wave64 b64 minimum, no extra conflicts).
    __shared__ float lds[256 * 38];
    float* sl0 = &lds[threadIdx.x * 38u];
    float* sl1 = sl0 + 18;

    const int idx0 = blockIdx.x * blockDim.x + threadIdx.x;
    const int stride = gridDim.x * blockDim.x;
    const int idx1 = idx0 + stride;
    const int mlast = M - 1;
    const int i0 = idx0 < M ? idx0 : mlast;
    const int i1 = idx1 < M ? idx1 : mlast;

    // single straight-line path: OOB lanes process a clamped element with
    // mf forced to 0 (contributes nothing)
    EIn e0, e1;
    load_elem(e0, pred_iou, pred_boxes, gt_boxes, mask, i0, idx0 < M);
    load_elem(e1, pred_iou, pred_boxes, gt_boxes, mask, i1, idx1 < M);
    float contrib = elem_body(e0, sl0) + elem_body(e1, sl1);
    float mfv = e0.mf + e1.mf;

    // block reduction: wave shuffle -> LDS -> one atomic pair per block
    #pragma unroll
    for (int off = 32; off > 0; off >>= 1) {
        contrib += __shfl_down(contrib, off, 64);
        mfv     += __shfl_down(mfv, off, 64);
    }
    __shared__ float sC[4], sM[4];
    const int lane = threadIdx.x & 63;
    const int wv = threadIdx.x >> 6;
    if (lane == 0) { sC[wv] = contrib; sM[wv] = mfv; }
    __syncthreads();
    if (threadIdx.x == 0) {
        float tc = sC[0] + sC[1] + sC[2] + sC[3];
        float tm = sM[0] + sM[1] + sM[2] + sM[3];
        atomicAdd(&sums[0], tc);
        atomicAdd(&sums[1], tm);
    }
}

__global__ void finalize_kernel(const float* __restrict__ sums, float* __restrict__ out) {
    if (threadIdx.x == 0 && blockIdx.x == 0)
        out[0] = sums[0] / fmaxf(sums[1], 1e-4f);
}

extern "C" void kernel_launch(void* const* d_in, const int* in_sizes, int n_in,
                              void* d_out, int out_size, void* d_ws, size_t ws_size,
                              hipStream_t stream) {
    const float* pred_iou   = (const float*)d_in[0];
    const float* pred_boxes = (const float*)d_in[1];
    const float* gt_boxes   = (const float*)d_in[2];
    const int*   mask       = (const int*)d_in[3];
    float* out  = (float*)d_out;
    float* sums = (float*)d_ws;
    const int M = in_sizes[0];

    hipMemsetAsync(sums, 0, 2 * sizeof(float), stream);
    const int block = 256;
    const int elems_per_thread = 2;
    int grid = (M + block * elems_per_thread - 1) / (block * elems_per_thread);
    if (grid < 1) grid = 1;
    hipLaunchKernelGGL(iou3d_loss_kernel, dim3(grid), dim3(block), 0, stream,
                       pred_iou, pred_boxes, gt_boxes, mask, sums, M);
    hipLaunchKernelGGL(finalize_kernel, dim3(1), dim3(64), 0, stream, sums, out);
}